// Round 11
// baseline (183.929 us; speedup 1.0000x reference)
//
#include <hip/hip_runtime.h>
#include <hip/hip_fp16.h>

#define N_    8
#define CIN   128
#define COUT  128
#define H_    128
#define W_    128
#define HO    126
#define WO    126
#define PIXPER (HO*WO)            // 15876
#define TOTPIX (N_*PIXPER)        // 127008
#define PT    128                 // pixels per block
#define BLKPERIMG 125             // ceil(15876/128): last block has 4 valid px
#define NBLK  (N_*BLKPERIMG)      // 1000; bid&7 = image -> XCD-local L2 reuse

typedef _Float16 f16x8 __attribute__((ext_vector_type(8)));
typedef _Float16 f16x4 __attribute__((ext_vector_type(4)));
typedef float    f32x4 __attribute__((ext_vector_type(4)));

union U4H {
    uint4   u;
    __half2 h[4];
    f16x8   f;
};
union U2H {
    uint2  u;
    __half h[4];
};

// global->LDS async, 16B per lane; LDS dest = wave-uniform base + lane*16
#define GLLDS(gp, lp) __builtin_amdgcn_global_load_lds( \
    (const __attribute__((address_space(1))) unsigned int*)(gp), \
    (__attribute__((address_space(3))) unsigned int*)(lp), 16, 0, 0)

// ---------------------------------------------------------------------------
// Kernel: input [N][C][H*W] fp32 -> channels-last fp16 [N][H*W][C]
// (unchanged — known-good)
// ---------------------------------------------------------------------------
__global__ __launch_bounds__(256) void transpose_in_kernel(
    const float* __restrict__ in, _Float16* __restrict__ in_cl)
{
    __shared__ float tile[64][65];
    int bid = blockIdx.x;
    int hwt = bid & 255;          // HW/64 = 256
    int ct  = (bid >> 8) & 1;     // C/64 = 2
    int n   = bid >> 9;           // N = 8
    int r0  = threadIdx.x >> 4;   // 0..15
    int c4  = (threadIdx.x & 15) * 4;
    const float* src = in + ((size_t)(n * CIN + ct * 64) * 16384) + hwt * 64;
#pragma unroll
    for (int k = 0; k < 4; ++k) {
        int row = r0 + k * 16;                      // c within tile
        float4 v = *(const float4*)(src + (size_t)row * 16384 + c4);
        *(float4*)&tile[row][c4] = v;               // [c][hw]
    }
    __syncthreads();
    _Float16* dst = in_cl + ((size_t)(n * 16384 + hwt * 64) * 128) + ct * 64;
#pragma unroll
    for (int k = 0; k < 4; ++k) {
        int hw = r0 + k * 16;
        f16x4 o;
        o[0] = (_Float16)tile[c4 + 0][hw];
        o[1] = (_Float16)tile[c4 + 1][hw];
        o[2] = (_Float16)tile[c4 + 2][hw];
        o[3] = (_Float16)tile[c4 + 3][hw];
        *(f16x4*)(dst + (size_t)hw * 128 + c4) = o;
    }
}

// ---------------------------------------------------------------------------
// Kernel: weight [O][C][3][3] fp32 -> wt [tap][swizzled O*C] fp16.
// Pre-swizzled so adc_main's staging is a LINEAR copy (global_load_lds-able)
// and the MFMA-phase read keeps the conflict-spread XOR pattern.
// Element (o, c) lands at uint4-index (o<<4)|((c>>3)^(o&7)), half (c&7).
// (v4-proven correct.)
// ---------------------------------------------------------------------------
__global__ void transpose_w_kernel(const float* __restrict__ w, _Float16* __restrict__ wt) {
    int t = blockIdx.x * 256 + threadIdx.x;   // 16384 threads
    int o = t >> 7, c = t & 127;
    int g = c >> 3;
    int dst = (((o << 4) | (g ^ (o & 7))) << 3) | (c & 7);
    const float* s = w + (size_t)(o * 128 + c) * 9;
#pragma unroll
    for (int tap = 0; tap < 9; ++tap)
        wt[tap * 16384 + dst] = (_Float16)s[tap];
}

// ---------------------------------------------------------------------------
// Gather helpers (v6's param read path; the ONLY change vs v4 in this file).
// Each 16-lane group (grp) owns 8 px; lane gl loads the 16B channel-chunk gl
// of each needed corner row (coalesced, 2 segments/instr).
// Addresses: PRE-CLAMPED + PRE-MULTIPLIED sPYp/sPXp (b32 broadcast):
// addr = (nbase + y + x)<<7 + lo.
// Lerp weights: PRECOMPUTED PRODUCTS (masks baked in, v5-proven correct)
// read as one b64 broadcast.
// ---------------------------------------------------------------------------
__device__ __forceinline__ void gather_issue(
    int KH, int KW, U4H (&G)[4][4], int j0, int grp, int gl, unsigned nbase,
    const _Float16* __restrict__ in_cl,
    const unsigned (*sPYp)[PT], const unsigned (*sPXp)[PT])
{
    const unsigned lo = (unsigned)(gl * 8);
#pragma unroll
    for (int jj = 0; jj < 4; ++jj) {
        int px = grp * 8 + j0 + jj;
        unsigned yp = sPYp[KH][px], xp = sPXp[KW][px];
        unsigned y0 = yp & 0xffffu, y1 = yp >> 16;   // pre-multiplied by W_
        unsigned x0 = xp & 0xffffu, x1 = xp >> 16;
        G[jj][0].u = *(const uint4*)(in_cl + (((nbase + y0 + x0) << 7) + lo));
        if (KW != 0)
            G[jj][1].u = *(const uint4*)(in_cl + (((nbase + y0 + x1) << 7) + lo));
        if (KH != 0)
            G[jj][2].u = *(const uint4*)(in_cl + (((nbase + y1 + x0) << 7) + lo));
        if (KH != 0 && KW != 0)
            G[jj][3].u = *(const uint4*)(in_cl + (((nbase + y1 + x1) << 7) + lo));
    }
}

__device__ __forceinline__ void gather_lerp_store(
    int TAP, int KH, int KW, U4H (&G)[4][4], int j0, int grp, int gl,
    _Float16* sS, const uint2 (*sPW)[PT])
{
#pragma unroll
    for (int jj = 0; jj < 4; ++jj) {
        int j  = j0 + jj;                 // 0..7  (== px & 7)
        int px = grp * 8 + j;
        U4H S;
        if (KH == 0 && KW == 0) {
            S = G[jj][0];                 // w00==1 exactly: passthrough
        } else {
            U2H W4;
            W4.u = sPW[TAP][px];          // b64 LDS broadcast (same addr/group)
            __half2 w00 = __half2half2(W4.h[0]);
            __half2 w01 = __half2half2(W4.h[1]);
            __half2 w10 = __half2half2(W4.h[2]);
            __half2 w11 = __half2half2(W4.h[3]);
#pragma unroll
            for (int d = 0; d < 4; ++d) {
                __half2 s = __hmul2(G[jj][0].h[d], w00);
                if (KW != 0)              s = __hfma2(G[jj][1].h[d], w01, s);
                if (KH != 0)              s = __hfma2(G[jj][2].h[d], w10, s);
                if (KH != 0 && KW != 0)   s = __hfma2(G[jj][3].h[d], w11, s);
                S.h[d] = s;
            }
        }
        // XOR chunk-swizzle: phys 16B-chunk = gl ^ (px&7); px&7 == j here.
        *(f16x8*)&sS[px * 128 + ((unsigned)(gl ^ j)) * 8] = S.f;
    }
}

// ---------------------------------------------------------------------------
// Main kernel v7 — DECOMPOSITION experiment.
// v6 (params+2x2 tiling) and v5 (params+A-from-L2) were BOTH ~40us slower
// than v4 with every pipe LESS busy; the param scheme is the confounded
// common factor. v7 isolates it: v4's structure EXACTLY (acc[8][2], 1x4
// phase-B tiling b0/b1, v4 epilogue, v4 prefetch schedule) + ONLY the
// sPW/sPYp/sPXp param scheme.
//   v7 fast (~75us) -> params good, v6's tiling was the toxin.
//   v7 slow (~120us) -> params toxic, revert to v4 next round.
// LDS: sW 32K + sS 32K + sPW 9K + sPYp/sPXp 3K = 76K -> 2 blocks/CU.
// ---------------------------------------------------------------------------
__global__ __launch_bounds__(256, 2) void adc_main(
    const _Float16* __restrict__ in_cl, const _Float16* __restrict__ wt,
    const float* __restrict__ rates, const float* __restrict__ bias,
    float* __restrict__ out)
{
    __shared__ uint4    sW[2048];                       // 32768 B
    __shared__ __align__(16) _Float16 sS[PT * 128];     // 32768 B, swizzled
    __shared__ uint2    sPW[9][PT];                     // 9216 B  w00..w11
    __shared__ unsigned sPYp[3][PT];                    // 1536 B  (yc1*W)<<16|yc0*W
    __shared__ unsigned sPXp[3][PT];                    // 1536 B  xc1<<16|xc0

    const int t    = threadIdx.x;
    const int lane = t & 63;
    const int wv   = t >> 6;
    const int l15  = lane & 15;
    const int quad = lane >> 4;

    const int n     = blockIdx.x & 7;
    const int pbase = (blockIdx.x >> 3) * PT;
    const unsigned nbase = (unsigned)n << 14;

    // ---- once-per-block params: rate bilinear + packed addrs + products ----
    if (t < PT) {
        int rem = min(pbase + t, PIXPER - 1);
        int ho = rem / WO, wo = rem - ho * WO;
        const float sc = 32.0f / 126.0f;
        float sy = fminf(fmaxf(((float)ho + 0.5f) * sc - 0.5f, 0.0f), 31.0f);
        float sx = fminf(fmaxf(((float)wo + 0.5f) * sc - 0.5f, 0.0f), 31.0f);
        int y0r = (int)sy, x0r = (int)sx;
        int y1r = min(y0r + 1, 31), x1r = min(x0r + 1, 31);
        float wyr = sy - (float)y0r, wxr = sx - (float)x0r;
        float r = rates[y0r * 32 + x0r] * (1.0f - wyr) * (1.0f - wxr)
                + rates[y0r * 32 + x1r] * (1.0f - wyr) * wxr
                + rates[y1r * 32 + x0r] * wyr * (1.0f - wxr)
                + rates[y1r * 32 + x1r] * wyr * wxr;
        float hy0[3], hy1[3], hx0[3], hx1[3];
#pragma unroll
        for (int k = 0; k < 3; ++k) {
            float fy  = (float)ho + (float)k * r;   // exact int when k==0
            float fy0 = floorf(fy);
            int   y0  = (int)fy0;
            float wy  = fy - fy0;
            int yc0 = min(y0, H_ - 1), yc1 = min(y0 + 1, H_ - 1);
            sPYp[k][t] = ((unsigned)(yc1 * W_) << 16) | (unsigned)(yc0 * W_);
            hy0[k] = (1.0f - wy) * ((y0 <= H_ - 1) ? 1.0f : 0.0f);
            hy1[k] = wy          * ((y0 <= H_ - 2) ? 1.0f : 0.0f);
            float fx  = (float)wo + (float)k * r;
            float fx0 = floorf(fx);
            int   x0  = (int)fx0;
            float wx  = fx - fx0;
            int xc0 = min(x0, W_ - 1), xc1 = min(x0 + 1, W_ - 1);
            sPXp[k][t] = ((unsigned)xc1 << 16) | (unsigned)xc0;
            hx0[k] = (1.0f - wx) * ((x0 <= W_ - 1) ? 1.0f : 0.0f);
            hx1[k] = wx          * ((x0 <= W_ - 2) ? 1.0f : 0.0f);
        }
#pragma unroll
        for (int kh = 0; kh < 3; ++kh)
#pragma unroll
            for (int kw = 0; kw < 3; ++kw) {
                U2H W4;
                W4.h[0] = __float2half(hy0[kh] * hx0[kw]);
                W4.h[1] = __float2half(hy0[kh] * hx1[kw]);
                W4.h[2] = __float2half(hy1[kh] * hx0[kw]);
                W4.h[3] = __float2half(hy1[kh] * hx1[kw]);
                sPW[kh * 3 + kw][t] = W4.u;
            }
    }

    f32x4 acc[8][2];                       // v4's accumulator layout
    const f32x4 zero = {0.0f, 0.0f, 0.0f, 0.0f};
#pragma unroll
    for (int i = 0; i < 8; ++i) { acc[i][0] = zero; acc[i][1] = zero; }

    const int grp = t >> 4;        // 16 row-groups
    const int gl  = t & 15;        // lane in group: channel chunk gl*8..gl*8+8

    __syncthreads();               // params ready

    U4H G[4][4];                   // 4 px x 4 corners in flight (<=64 VGPR)

    // prologue: issue tap0 batch0
    gather_issue(0, 0, G, 0, grp, gl, nbase, in_cl, sPYp, sPXp);

#pragma unroll
    for (int tap = 0; tap < 9; ++tap) {
        const int kh = tap / 3;            // compile-time after unroll
        const int kw = tap - kh * 3;

        // ---- stage W[tap]: linear async copy, issued early (hides latency
        //      under the lerp/batch1 work below; prev MFMA done at barrier2) --
        const uint4* wsrc = (const uint4*)(wt + tap * 16384);
#pragma unroll
        for (int i = 0; i < 8; ++i) {
            int base = i * 256 + (wv << 6);
            GLLDS(wsrc + base + lane, &sW[base]);
        }

        // ---- phase A: batch0 (in flight since prev MFMA), then batch1 ----
        gather_lerp_store(tap, kh, kw, G, 0, grp, gl, sS, sPW);
        gather_issue(kh, kw, G, 4, grp, gl, nbase, in_cl, sPYp, sPXp);
        gather_lerp_store(tap, kh, kw, G, 4, grp, gl, sS, sPW);

        __syncthreads();                   // drains glds+gathers; sS+sW ready

        // ---- prefetch next tap's batch0 (flies during MFMA) ----
        if (tap < 8) {
            const int tap1 = tap + 1;
            const int kh1 = tap1 / 3;
            const int kw1 = tap1 - kh1 * 3;
            gather_issue(kh1, kw1, G, 0, grp, gl, nbase, in_cl, sPYp, sPXp);
        }

        // ---- phase B: MFMA, v4's 1x4 tiling (full o-range, wv row slice) ----
#pragma unroll
        for (int ks = 0; ks < 4; ++ks) {
            const int sw = ((ks << 2) | quad) ^ (l15 & 7);
            f16x8 b0 = *(const f16x8*)&sS[(wv * 32 +      l15) * 128 + sw * 8];
            f16x8 b1 = *(const f16x8*)&sS[(wv * 32 + 16 + l15) * 128 + sw * 8];
#pragma unroll
            for (int mt = 0; mt < 8; ++mt) {
                int o = (mt << 4) | l15;
                U4H AF;
                AF.u = sW[(o << 4) | sw];  // o&7 == l15&7
                acc[mt][0] = __builtin_amdgcn_mfma_f32_16x16x32_f16(AF.f, b0, acc[mt][0], 0, 0, 0);
                acc[mt][1] = __builtin_amdgcn_mfma_f32_16x16x32_f16(AF.f, b1, acc[mt][1], 0, 0, 0);
            }
        }
        __syncthreads();                   // protect sS/sW overwrite next tap
    }

    // ---- epilogue: v4's direct strided stores ----
#pragma unroll
    for (int pt = 0; pt < 2; ++pt) {
        int p    = (wv << 5) + (pt << 4) + l15;
        int prel = pbase + p;
        int rem2 = min(prel, PIXPER - 1);
        float* obase = out + (size_t)n * (COUT * PIXPER) + rem2;
        if (prel < PIXPER) {
#pragma unroll
            for (int mt = 0; mt < 8; ++mt) {
                int o0 = (mt << 4) + (quad << 2);
                float4 bs = *(const float4*)(bias + o0);
                f32x4 a0 = acc[mt][pt];
                obase[(size_t)(o0 + 0) * PIXPER] = a0[0] + bs.x;
                obase[(size_t)(o0 + 1) * PIXPER] = a0[1] + bs.y;
                obase[(size_t)(o0 + 2) * PIXPER] = a0[2] + bs.z;
                obase[(size_t)(o0 + 3) * PIXPER] = a0[3] + bs.w;
            }
        }
    }
}

// ---------------------------------------------------------------------------
extern "C" void kernel_launch(void* const* d_in, const int* in_sizes, int n_in,
                              void* d_out, int out_size, void* d_ws, size_t ws_size,
                              hipStream_t stream) {
    const float* inputs = (const float*)d_in[0];   // [8,128,128,128]
    const float* weight = (const float*)d_in[1];   // [128,128,3,3]
    const float* rates  = (const float*)d_in[2];   // [1,1,32,32]
    const float* bias   = (const float*)d_in[3];   // [128]
    float* out = (float*)d_out;                    // [8,128,126,126]

    char* ws = (char*)d_ws;
    _Float16* in_cl = (_Float16*)ws;                         // 33,554,432 B
    _Float16* wtp   = (_Float16*)(ws + 33554432);            //    294,912 B

    transpose_w_kernel<<<64, 256, 0, stream>>>(weight, wtp);
    transpose_in_kernel<<<4096, 256, 0, stream>>>(inputs, in_cl);
    adc_main<<<NBLK, 256, 0, stream>>>(in_cl, wtp, rates, bias, out);
}

// Round 12
// 183.446 us; speedup vs baseline: 1.0026x; 1.0026x over previous
//
#include <hip/hip_runtime.h>
#include <hip/hip_fp16.h>

#define N_    8
#define CIN   128
#define COUT  128
#define H_    128
#define W_    128
#define HO    126
#define WO    126
#define PIXPER (HO*WO)            // 15876
#define TOTPIX (N_*PIXPER)        // 127008
#define PT    128                 // pixels per block
#define BLKPERIMG 125             // ceil(15876/128): last block has 4 valid px
#define NBLK  (N_*BLKPERIMG)      // 1000; bid&7 = image -> XCD-local L2 reuse

typedef _Float16 f16x8 __attribute__((ext_vector_type(8)));
typedef _Float16 f16x4 __attribute__((ext_vector_type(4)));
typedef float    f32x4 __attribute__((ext_vector_type(4)));

union U4H {
    uint4   u;
    __half2 h[4];
    f16x8   f;
};
union U2H {
    uint2  u;
    __half h[4];
};

// global->LDS async, 16B per lane; LDS dest = wave-uniform base + lane*16
#define GLLDS(gp, lp) __builtin_amdgcn_global_load_lds( \
    (const __attribute__((address_space(1))) unsigned int*)(gp), \
    (__attribute__((address_space(3))) unsigned int*)(lp), 16, 0, 0)

// ---------------------------------------------------------------------------
// Kernel: input [N][C][H*W] fp32 -> channels-last fp16 [N][H*W][C]
// (unchanged — known-good)
// ---------------------------------------------------------------------------
__global__ __launch_bounds__(256) void transpose_in_kernel(
    const float* __restrict__ in, _Float16* __restrict__ in_cl)
{
    __shared__ float tile[64][65];
    int bid = blockIdx.x;
    int hwt = bid & 255;          // HW/64 = 256
    int ct  = (bid >> 8) & 1;     // C/64 = 2
    int n   = bid >> 9;           // N = 8
    int r0  = threadIdx.x >> 4;   // 0..15
    int c4  = (threadIdx.x & 15) * 4;
    const float* src = in + ((size_t)(n * CIN + ct * 64) * 16384) + hwt * 64;
#pragma unroll
    for (int k = 0; k < 4; ++k) {
        int row = r0 + k * 16;                      // c within tile
        float4 v = *(const float4*)(src + (size_t)row * 16384 + c4);
        *(float4*)&tile[row][c4] = v;               // [c][hw]
    }
    __syncthreads();
    _Float16* dst = in_cl + ((size_t)(n * 16384 + hwt * 64) * 128) + ct * 64;
#pragma unroll
    for (int k = 0; k < 4; ++k) {
        int hw = r0 + k * 16;
        f16x4 o;
        o[0] = (_Float16)tile[c4 + 0][hw];
        o[1] = (_Float16)tile[c4 + 1][hw];
        o[2] = (_Float16)tile[c4 + 2][hw];
        o[3] = (_Float16)tile[c4 + 3][hw];
        *(f16x4*)(dst + (size_t)hw * 128 + c4) = o;
    }
}

// ---------------------------------------------------------------------------
// Kernel: weight [O][C][3][3] fp32 -> wtA, A-FRAGMENT-MAJOR fp16 (v5-proven):
// wtA half-index = (((tap*8+mt)*4+ks)*64 + lane)*8 + d, where
// o = mt*16+l15, c = ks*32+quad*8+d, lane = quad*16+l15.
// In adc_main phase B, each (mt,ks) A-frag read from LDS becomes
// base + lane*16B — perfectly LINEAR -> conflict-free (2 lanes/bank).
// Staging stays a linear global_load_lds copy (16KB x2 per tap).
// ---------------------------------------------------------------------------
__global__ void transpose_w_kernel(const float* __restrict__ w, _Float16* __restrict__ wt) {
    int t = blockIdx.x * 256 + threadIdx.x;   // 16384 threads: o*128 + c
    int o = t >> 7, c = t & 127;
    int mt = o >> 4, l15 = o & 15;
    int ks = c >> 5, quad = (c >> 3) & 3, d = c & 7;
    int lane = (quad << 4) | l15;
    const float* s = w + (size_t)(o * 128 + c) * 9;
#pragma unroll
    for (int tap = 0; tap < 9; ++tap) {
        int idx = ((((tap * 8 + mt) * 4 + ks) << 6) + lane) * 8 + d;
        wt[idx] = (_Float16)s[tap];
    }
}

// ---------------------------------------------------------------------------
// Gather helpers (v7-proven). Each 16-lane group (grp) owns 8 px; lane gl
// loads the 16B channel-chunk gl of each needed corner row (coalesced).
// Addresses: PRE-CLAMPED + PRE-MULTIPLIED sPYp/sPXp (b32 broadcast).
// Lerp weights: PRECOMPUTED PRODUCTS (masks baked in) read as one b64
// broadcast.
// ---------------------------------------------------------------------------
__device__ __forceinline__ void gather_issue(
    int KH, int KW, U4H (&G)[4][4], int j0, int grp, int gl, unsigned nbase,
    const _Float16* __restrict__ in_cl,
    const unsigned (*sPYp)[PT], const unsigned (*sPXp)[PT])
{
    const unsigned lo = (unsigned)(gl * 8);
#pragma unroll
    for (int jj = 0; jj < 4; ++jj) {
        int px = grp * 8 + j0 + jj;
        unsigned yp = sPYp[KH][px], xp = sPXp[KW][px];
        unsigned y0 = yp & 0xffffu, y1 = yp >> 16;   // pre-multiplied by W_
        unsigned x0 = xp & 0xffffu, x1 = xp >> 16;
        G[jj][0].u = *(const uint4*)(in_cl + (((nbase + y0 + x0) << 7) + lo));
        if (KW != 0)
            G[jj][1].u = *(const uint4*)(in_cl + (((nbase + y0 + x1) << 7) + lo));
        if (KH != 0)
            G[jj][2].u = *(const uint4*)(in_cl + (((nbase + y1 + x0) << 7) + lo));
        if (KH != 0 && KW != 0)
            G[jj][3].u = *(const uint4*)(in_cl + (((nbase + y1 + x1) << 7) + lo));
    }
}

__device__ __forceinline__ void gather_lerp_store(
    int TAP, int KH, int KW, U4H (&G)[4][4], int j0, int grp, int gl,
    _Float16* sS, const uint2 (*sPW)[PT])
{
#pragma unroll
    for (int jj = 0; jj < 4; ++jj) {
        int j  = j0 + jj;                 // 0..7  (== px & 7)
        int px = grp * 8 + j;
        U4H S;
        if (KH == 0 && KW == 0) {
            S = G[jj][0];                 // w00==1 exactly: passthrough
        } else {
            U2H W4;
            W4.u = sPW[TAP][px];          // b64 LDS broadcast (same addr/group)
            __half2 w00 = __half2half2(W4.h[0]);
            __half2 w01 = __half2half2(W4.h[1]);
            __half2 w10 = __half2half2(W4.h[2]);
            __half2 w11 = __half2half2(W4.h[3]);
#pragma unroll
            for (int d = 0; d < 4; ++d) {
                __half2 s = __hmul2(G[jj][0].h[d], w00);
                if (KW != 0)              s = __hfma2(G[jj][1].h[d], w01, s);
                if (KH != 0)              s = __hfma2(G[jj][2].h[d], w10, s);
                if (KH != 0 && KW != 0)   s = __hfma2(G[jj][3].h[d], w11, s);
                S.h[d] = s;
            }
        }
        // XOR chunk-swizzle: phys 16B-chunk = gl ^ (px&7); px&7 == j here.
        *(f16x8*)&sS[px * 128 + ((unsigned)(gl ^ j)) * 8] = S.f;
    }
}

// ---------------------------------------------------------------------------
// Main kernel v8 = v7 (best measured: 80.6us) + conflict-free sW reads.
// v7's sW read sW[(o<<4)|sw] has bank-start = (sw%8)*4 only -> every MFMA
// A-read is a structural 8-way conflict (32 reads/wave/tap = the 4.6M
// conflict cycles v3 isolated). v8 stores the tap in A-FRAGMENT-MAJOR order
// (layout v5-proven): read = sW[(mt*4+ks)*64 + lane] = base + lane*16B,
// linear -> 2 lanes/bank (free). Staging remains a linear GLLDS copy.
// sS's 8-way pattern is structural (px-major writes vs k-major reads at 16B
// granularity) and only 8 reads/wave/tap — left as-is.
// LDS: sW 32K + sS 32K + sPW 9K + sPYp/sPXp 3K = 76.8K -> 2 blocks/CU.
// ---------------------------------------------------------------------------
__global__ __launch_bounds__(256, 2) void adc_main(
    const _Float16* __restrict__ in_cl, const _Float16* __restrict__ wtA,
    const float* __restrict__ rates, const float* __restrict__ bias,
    float* __restrict__ out)
{
    __shared__ uint4    sW[2048];                       // 32768 B, frag-major
    __shared__ __align__(16) _Float16 sS[PT * 128];     // 32768 B, swizzled
    __shared__ uint2    sPW[9][PT];                     // 9216 B  w00..w11
    __shared__ unsigned sPYp[3][PT];                    // 1536 B  (yc1*W)<<16|yc0*W
    __shared__ unsigned sPXp[3][PT];                    // 1536 B  xc1<<16|xc0

    const int t    = threadIdx.x;
    const int lane = t & 63;
    const int wv   = t >> 6;
    const int l15  = lane & 15;
    const int quad = lane >> 4;

    const int n     = blockIdx.x & 7;
    const int pbase = (blockIdx.x >> 3) * PT;
    const unsigned nbase = (unsigned)n << 14;

    // ---- once-per-block params: rate bilinear + packed addrs + products ----
    if (t < PT) {
        int rem = min(pbase + t, PIXPER - 1);
        int ho = rem / WO, wo = rem - ho * WO;
        const float sc = 32.0f / 126.0f;
        float sy = fminf(fmaxf(((float)ho + 0.5f) * sc - 0.5f, 0.0f), 31.0f);
        float sx = fminf(fmaxf(((float)wo + 0.5f) * sc - 0.5f, 0.0f), 31.0f);
        int y0r = (int)sy, x0r = (int)sx;
        int y1r = min(y0r + 1, 31), x1r = min(x0r + 1, 31);
        float wyr = sy - (float)y0r, wxr = sx - (float)x0r;
        float r = rates[y0r * 32 + x0r] * (1.0f - wyr) * (1.0f - wxr)
                + rates[y0r * 32 + x1r] * (1.0f - wyr) * wxr
                + rates[y1r * 32 + x0r] * wyr * (1.0f - wxr)
                + rates[y1r * 32 + x1r] * wyr * wxr;
        float hy0[3], hy1[3], hx0[3], hx1[3];
#pragma unroll
        for (int k = 0; k < 3; ++k) {
            float fy  = (float)ho + (float)k * r;   // exact int when k==0
            float fy0 = floorf(fy);
            int   y0  = (int)fy0;
            float wy  = fy - fy0;
            int yc0 = min(y0, H_ - 1), yc1 = min(y0 + 1, H_ - 1);
            sPYp[k][t] = ((unsigned)(yc1 * W_) << 16) | (unsigned)(yc0 * W_);
            hy0[k] = (1.0f - wy) * ((y0 <= H_ - 1) ? 1.0f : 0.0f);
            hy1[k] = wy          * ((y0 <= H_ - 2) ? 1.0f : 0.0f);
            float fx  = (float)wo + (float)k * r;
            float fx0 = floorf(fx);
            int   x0  = (int)fx0;
            float wx  = fx - fx0;
            int xc0 = min(x0, W_ - 1), xc1 = min(x0 + 1, W_ - 1);
            sPXp[k][t] = ((unsigned)xc1 << 16) | (unsigned)xc0;
            hx0[k] = (1.0f - wx) * ((x0 <= W_ - 1) ? 1.0f : 0.0f);
            hx1[k] = wx          * ((x0 <= W_ - 2) ? 1.0f : 0.0f);
        }
#pragma unroll
        for (int kh = 0; kh < 3; ++kh)
#pragma unroll
            for (int kw = 0; kw < 3; ++kw) {
                U2H W4;
                W4.h[0] = __float2half(hy0[kh] * hx0[kw]);
                W4.h[1] = __float2half(hy0[kh] * hx1[kw]);
                W4.h[2] = __float2half(hy1[kh] * hx0[kw]);
                W4.h[3] = __float2half(hy1[kh] * hx1[kw]);
                sPW[kh * 3 + kw][t] = W4.u;
            }
    }

    f32x4 acc[8][2];                       // v4/v7 accumulator layout
    const f32x4 zero = {0.0f, 0.0f, 0.0f, 0.0f};
#pragma unroll
    for (int i = 0; i < 8; ++i) { acc[i][0] = zero; acc[i][1] = zero; }

    const int grp = t >> 4;        // 16 row-groups
    const int gl  = t & 15;        // lane in group: channel chunk gl*8..gl*8+8

    __syncthreads();               // params ready

    U4H G[4][4];                   // 4 px x 4 corners in flight (<=64 VGPR)

    // prologue: issue tap0 batch0
    gather_issue(0, 0, G, 0, grp, gl, nbase, in_cl, sPYp, sPXp);

#pragma unroll
    for (int tap = 0; tap < 9; ++tap) {
        const int kh = tap / 3;            // compile-time after unroll
        const int kw = tap - kh * 3;

        // ---- stage W[tap]: linear async copy of the frag-major tap block ----
        const uint4* wsrc = (const uint4*)wtA + tap * 2048;
#pragma unroll
        for (int i = 0; i < 8; ++i) {
            int base = i * 256 + (wv << 6);
            GLLDS(wsrc + base + lane, &sW[base]);
        }

        // ---- phase A: batch0 (in flight since prev MFMA), then batch1 ----
        gather_lerp_store(tap, kh, kw, G, 0, grp, gl, sS, sPW);
        gather_issue(kh, kw, G, 4, grp, gl, nbase, in_cl, sPYp, sPXp);
        gather_lerp_store(tap, kh, kw, G, 4, grp, gl, sS, sPW);

        __syncthreads();                   // drains glds+gathers; sS+sW ready

        // ---- prefetch next tap's batch0 (flies during MFMA) ----
        if (tap < 8) {
            const int tap1 = tap + 1;
            const int kh1 = tap1 / 3;
            const int kw1 = tap1 - kh1 * 3;
            gather_issue(kh1, kw1, G, 0, grp, gl, nbase, in_cl, sPYp, sPXp);
        }

        // ---- phase B: MFMA, A-frags LINEAR from sW (conflict-free) ----
#pragma unroll
        for (int ks = 0; ks < 4; ++ks) {
            const int sw = ((ks << 2) | quad) ^ (l15 & 7);
            f16x8 b0 = *(const f16x8*)&sS[(wv * 32 +      l15) * 128 + sw * 8];
            f16x8 b1 = *(const f16x8*)&sS[(wv * 32 + 16 + l15) * 128 + sw * 8];
#pragma unroll
            for (int mt = 0; mt < 8; ++mt) {
                U4H AF;
                AF.u = sW[((mt << 2) | ks) * 64 + lane];   // base + lane*16B
                acc[mt][0] = __builtin_amdgcn_mfma_f32_16x16x32_f16(AF.f, b0, acc[mt][0], 0, 0, 0);
                acc[mt][1] = __builtin_amdgcn_mfma_f32_16x16x32_f16(AF.f, b1, acc[mt][1], 0, 0, 0);
            }
        }
        __syncthreads();                   // protect sS/sW overwrite next tap
    }

    // ---- epilogue: v4's direct strided stores ----
#pragma unroll
    for (int pt = 0; pt < 2; ++pt) {
        int p    = (wv << 5) + (pt << 4) + l15;
        int prel = pbase + p;
        int rem2 = min(prel, PIXPER - 1);
        float* obase = out + (size_t)n * (COUT * PIXPER) + rem2;
        if (prel < PIXPER) {
#pragma unroll
            for (int mt = 0; mt < 8; ++mt) {
                int o0 = (mt << 4) + (quad << 2);
                float4 bs = *(const float4*)(bias + o0);
                f32x4 a0 = acc[mt][pt];
                obase[(size_t)(o0 + 0) * PIXPER] = a0[0] + bs.x;
                obase[(size_t)(o0 + 1) * PIXPER] = a0[1] + bs.y;
                obase[(size_t)(o0 + 2) * PIXPER] = a0[2] + bs.z;
                obase[(size_t)(o0 + 3) * PIXPER] = a0[3] + bs.w;
            }
        }
    }
}

// ---------------------------------------------------------------------------
extern "C" void kernel_launch(void* const* d_in, const int* in_sizes, int n_in,
                              void* d_out, int out_size, void* d_ws, size_t ws_size,
                              hipStream_t stream) {
    const float* inputs = (const float*)d_in[0];   // [8,128,128,128]
    const float* weight = (const float*)d_in[1];   // [128,128,3,3]
    const float* rates  = (const float*)d_in[2];   // [1,1,32,32]
    const float* bias   = (const float*)d_in[3];   // [128]
    float* out = (float*)d_out;                    // [8,128,126,126]

    char* ws = (char*)d_ws;
    _Float16* in_cl = (_Float16*)ws;                         // 33,554,432 B
    _Float16* wtp   = (_Float16*)(ws + 33554432);            //    294,912 B

    transpose_w_kernel<<<64, 256, 0, stream>>>(weight, wtp);
    transpose_in_kernel<<<4096, 256, 0, stream>>>(inputs, in_cl);
    adc_main<<<NBLK, 256, 0, stream>>>(in_cl, wtp, rates, bias, out);
}

// Round 13
// 178.935 us; speedup vs baseline: 1.0279x; 1.0252x over previous
//
#include <hip/hip_runtime.h>
#include <hip/hip_fp16.h>

#define N_    8
#define CIN   128
#define COUT  128
#define H_    128
#define W_    128
#define HO    126
#define WO    126
#define PIXPER (HO*WO)            // 15876
#define TOTPIX (N_*PIXPER)        // 127008
#define PT    128                 // pixels per block
#define BLKPERIMG 125             // ceil(15876/128): last block has 4 valid px
#define NBLK  (N_*BLKPERIMG)      // 1000; bid&7 = image -> XCD-local L2 reuse

typedef _Float16 f16x8 __attribute__((ext_vector_type(8)));
typedef _Float16 f16x4 __attribute__((ext_vector_type(4)));
typedef float    f32x4 __attribute__((ext_vector_type(4)));

union U4H {
    uint4   u;
    __half2 h[4];
    f16x8   f;
};
union U2H {
    uint2  u;
    __half h[4];
};

// global->LDS async, 16B per lane; LDS dest = wave-uniform base + lane*16
#define GLLDS(gp, lp) __builtin_amdgcn_global_load_lds( \
    (const __attribute__((address_space(1))) unsigned int*)(gp), \
    (__attribute__((address_space(3))) unsigned int*)(lp), 16, 0, 0)

// ---------------------------------------------------------------------------
// Kernel: input [N][C][H*W] fp32 -> channels-last fp16 [N][H*W][C]
// (unchanged — known-good)
// ---------------------------------------------------------------------------
__global__ __launch_bounds__(256) void transpose_in_kernel(
    const float* __restrict__ in, _Float16* __restrict__ in_cl)
{
    __shared__ float tile[64][65];
    int bid = blockIdx.x;
    int hwt = bid & 255;          // HW/64 = 256
    int ct  = (bid >> 8) & 1;     // C/64 = 2
    int n   = bid >> 9;           // N = 8
    int r0  = threadIdx.x >> 4;   // 0..15
    int c4  = (threadIdx.x & 15) * 4;
    const float* src = in + ((size_t)(n * CIN + ct * 64) * 16384) + hwt * 64;
#pragma unroll
    for (int k = 0; k < 4; ++k) {
        int row = r0 + k * 16;                      // c within tile
        float4 v = *(const float4*)(src + (size_t)row * 16384 + c4);
        *(float4*)&tile[row][c4] = v;               // [c][hw]
    }
    __syncthreads();
    _Float16* dst = in_cl + ((size_t)(n * 16384 + hwt * 64) * 128) + ct * 64;
#pragma unroll
    for (int k = 0; k < 4; ++k) {
        int hw = r0 + k * 16;
        f16x4 o;
        o[0] = (_Float16)tile[c4 + 0][hw];
        o[1] = (_Float16)tile[c4 + 1][hw];
        o[2] = (_Float16)tile[c4 + 2][hw];
        o[3] = (_Float16)tile[c4 + 3][hw];
        *(f16x4*)(dst + (size_t)hw * 128 + c4) = o;
    }
}

// ---------------------------------------------------------------------------
// Kernel: weight [O][C][3][3] fp32 -> wtA, A-FRAGMENT-MAJOR fp16 (v8-proven):
// wtA half-index = (((tap*8+mt)*4+ks)*64 + lane)*8 + d, where
// o = mt*16+l15, c = ks*32+quad*8+d, lane = quad*16+l15.
// Phase-B A-frag read = base + lane*16B — LINEAR, conflict-free.
// ---------------------------------------------------------------------------
__global__ void transpose_w_kernel(const float* __restrict__ w, _Float16* __restrict__ wt) {
    int t = blockIdx.x * 256 + threadIdx.x;   // 16384 threads: o*128 + c
    int o = t >> 7, c = t & 127;
    int mt = o >> 4, l15 = o & 15;
    int ks = c >> 5, quad = (c >> 3) & 3, d = c & 7;
    int lane = (quad << 4) | l15;
    const float* s = w + (size_t)(o * 128 + c) * 9;
#pragma unroll
    for (int tap = 0; tap < 9; ++tap) {
        int idx = ((((tap * 8 + mt) * 4 + ks) << 6) + lane) * 8 + d;
        wt[idx] = (_Float16)s[tap];
    }
}

// ---------------------------------------------------------------------------
// Gather helpers (v7-proven). Each 16-lane group (grp) owns 8 px; lane gl
// loads the 16B channel-chunk gl of each needed corner row (coalesced).
// Addresses: PRE-CLAMPED + PRE-MULTIPLIED sPYp/sPXp (b32 broadcast).
// Lerp weights: PRECOMPUTED PRODUCTS (masks baked in) as one b64 broadcast.
// ---------------------------------------------------------------------------
__device__ __forceinline__ void gather_issue(
    int KH, int KW, U4H (&G)[4][4], int j0, int grp, int gl, unsigned nbase,
    const _Float16* __restrict__ in_cl,
    const unsigned (*sPYp)[PT], const unsigned (*sPXp)[PT])
{
    const unsigned lo = (unsigned)(gl * 8);
#pragma unroll
    for (int jj = 0; jj < 4; ++jj) {
        int px = grp * 8 + j0 + jj;
        unsigned yp = sPYp[KH][px], xp = sPXp[KW][px];
        unsigned y0 = yp & 0xffffu, y1 = yp >> 16;   // pre-multiplied by W_
        unsigned x0 = xp & 0xffffu, x1 = xp >> 16;
        G[jj][0].u = *(const uint4*)(in_cl + (((nbase + y0 + x0) << 7) + lo));
        if (KW != 0)
            G[jj][1].u = *(const uint4*)(in_cl + (((nbase + y0 + x1) << 7) + lo));
        if (KH != 0)
            G[jj][2].u = *(const uint4*)(in_cl + (((nbase + y1 + x0) << 7) + lo));
        if (KH != 0 && KW != 0)
            G[jj][3].u = *(const uint4*)(in_cl + (((nbase + y1 + x1) << 7) + lo));
    }
}

__device__ __forceinline__ void gather_lerp_store(
    int TAP, int KH, int KW, U4H (&G)[4][4], int j0, int grp, int gl,
    _Float16* sS, const uint2 (*sPW)[PT])
{
#pragma unroll
    for (int jj = 0; jj < 4; ++jj) {
        int j  = j0 + jj;                 // 0..7  (== px & 7)
        int px = grp * 8 + j;
        U4H S;
        if (KH == 0 && KW == 0) {
            S = G[jj][0];                 // w00==1 exactly: passthrough
        } else {
            U2H W4;
            W4.u = sPW[TAP][px];          // b64 LDS broadcast (same addr/group)
            __half2 w00 = __half2half2(W4.h[0]);
            __half2 w01 = __half2half2(W4.h[1]);
            __half2 w10 = __half2half2(W4.h[2]);
            __half2 w11 = __half2half2(W4.h[3]);
#pragma unroll
            for (int d = 0; d < 4; ++d) {
                __half2 s = __hmul2(G[jj][0].h[d], w00);
                if (KW != 0)              s = __hfma2(G[jj][1].h[d], w01, s);
                if (KH != 0)              s = __hfma2(G[jj][2].h[d], w10, s);
                if (KH != 0 && KW != 0)   s = __hfma2(G[jj][3].h[d], w11, s);
                S.h[d] = s;
            }
        }
        // XOR chunk-swizzle: phys 16B-chunk = gl ^ (px&7); px&7 == j here.
        *(f16x8*)&sS[px * 128 + ((unsigned)(gl ^ j)) * 8] = S.f;
    }
}

// ---------------------------------------------------------------------------
// Main kernel v9 — reconciliation: v6's 2x2 wave-tiling (BEST bench total,
// 179.99us; its bad profile was contention-contaminated: all pipes depressed
// simultaneously) + v8's frag-major conflict-free A-reads + v7's params.
// Per wave per tap: 16 A-reads (linear, conflict-free) + 16 sS reads
// (8-way structural) = 32 LDS ops (vs 40 in v8), A-redundancy 2x (vs 4x).
// Decision rule: bench total <=180 confirms v6 anomaly theory -> next round
// attacks occupancy; >186 -> 2x2 genuinely toxic, revert permanently.
// LDS: sW 32K + sS 32K + sPW 9K + coords 3K = 76.8K -> 2 blocks/CU.
// ---------------------------------------------------------------------------
__global__ __launch_bounds__(256, 2) void adc_main(
    const _Float16* __restrict__ in_cl, const _Float16* __restrict__ wtA,
    const float* __restrict__ rates, const float* __restrict__ bias,
    float* __restrict__ out)
{
    __shared__ uint4    sW[2048];                       // 32768 B, frag-major
    __shared__ __align__(16) _Float16 sS[PT * 128];     // 32768 B, swizzled
    __shared__ uint2    sPW[9][PT];                     // 9216 B  w00..w11
    __shared__ unsigned sPYp[3][PT];                    // 1536 B  (yc1*W)<<16|yc0*W
    __shared__ unsigned sPXp[3][PT];                    // 1536 B  xc1<<16|xc0

    const int t    = threadIdx.x;
    const int lane = t & 63;
    const int wv   = t >> 6;
    const int l15  = lane & 15;
    const int quad = lane >> 4;

    const int n     = blockIdx.x & 7;
    const int pbase = (blockIdx.x >> 3) * PT;
    const unsigned nbase = (unsigned)n << 14;

    // ---- once-per-block params: rate bilinear + packed addrs + products ----
    if (t < PT) {
        int rem = min(pbase + t, PIXPER - 1);
        int ho = rem / WO, wo = rem - ho * WO;
        const float sc = 32.0f / 126.0f;
        float sy = fminf(fmaxf(((float)ho + 0.5f) * sc - 0.5f, 0.0f), 31.0f);
        float sx = fminf(fmaxf(((float)wo + 0.5f) * sc - 0.5f, 0.0f), 31.0f);
        int y0r = (int)sy, x0r = (int)sx;
        int y1r = min(y0r + 1, 31), x1r = min(x0r + 1, 31);
        float wyr = sy - (float)y0r, wxr = sx - (float)x0r;
        float r = rates[y0r * 32 + x0r] * (1.0f - wyr) * (1.0f - wxr)
                + rates[y0r * 32 + x1r] * (1.0f - wyr) * wxr
                + rates[y1r * 32 + x0r] * wyr * (1.0f - wxr)
                + rates[y1r * 32 + x1r] * wyr * wxr;
        float hy0[3], hy1[3], hx0[3], hx1[3];
#pragma unroll
        for (int k = 0; k < 3; ++k) {
            float fy  = (float)ho + (float)k * r;   // exact int when k==0
            float fy0 = floorf(fy);
            int   y0  = (int)fy0;
            float wy  = fy - fy0;
            int yc0 = min(y0, H_ - 1), yc1 = min(y0 + 1, H_ - 1);
            sPYp[k][t] = ((unsigned)(yc1 * W_) << 16) | (unsigned)(yc0 * W_);
            hy0[k] = (1.0f - wy) * ((y0 <= H_ - 1) ? 1.0f : 0.0f);
            hy1[k] = wy          * ((y0 <= H_ - 2) ? 1.0f : 0.0f);
            float fx  = (float)wo + (float)k * r;
            float fx0 = floorf(fx);
            int   x0  = (int)fx0;
            float wx  = fx - fx0;
            int xc0 = min(x0, W_ - 1), xc1 = min(x0 + 1, W_ - 1);
            sPXp[k][t] = ((unsigned)xc1 << 16) | (unsigned)xc0;
            hx0[k] = (1.0f - wx) * ((x0 <= W_ - 1) ? 1.0f : 0.0f);
            hx1[k] = wx          * ((x0 <= W_ - 2) ? 1.0f : 0.0f);
        }
#pragma unroll
        for (int kh = 0; kh < 3; ++kh)
#pragma unroll
            for (int kw = 0; kw < 3; ++kw) {
                U2H W4;
                W4.h[0] = __float2half(hy0[kh] * hx0[kw]);
                W4.h[1] = __float2half(hy0[kh] * hx1[kw]);
                W4.h[2] = __float2half(hy1[kh] * hx0[kw]);
                W4.h[3] = __float2half(hy1[kh] * hx1[kw]);
                sPW[kh * 3 + kw][t] = W4.u;
            }
    }

    f32x4 acc[4][4];                       // [mt][nt], 64 VGPRs (2x2 tile)
    const f32x4 zero = {0.0f, 0.0f, 0.0f, 0.0f};
#pragma unroll
    for (int i = 0; i < 4; ++i)
#pragma unroll
        for (int k = 0; k < 4; ++k) acc[i][k] = zero;

    const int grp = t >> 4;        // 16 row-groups
    const int gl  = t & 15;        // lane in group: channel chunk gl*8..gl*8+8
    const int wm  = wv >> 1;       // 2x2 wave tile: M-half (o 0..63 / 64..127)
    const int wn  = wv & 1;        //                N-half (px 0..63 / 64..127)

    __syncthreads();               // params ready

    U4H G[4][4];                   // 4 px x 4 corners in flight (<=64 VGPR)

    // prologue: issue tap0 batch0
    gather_issue(0, 0, G, 0, grp, gl, nbase, in_cl, sPYp, sPXp);

#pragma unroll
    for (int tap = 0; tap < 9; ++tap) {
        const int kh = tap / 3;            // compile-time after unroll
        const int kw = tap - kh * 3;

        // ---- stage W[tap]: linear async copy of the frag-major tap block ----
        const uint4* wsrc = (const uint4*)wtA + tap * 2048;
#pragma unroll
        for (int i = 0; i < 8; ++i) {
            int base = i * 256 + (wv << 6);
            GLLDS(wsrc + base + lane, &sW[base]);
        }

        // ---- phase A: batch0 (in flight since prev MFMA), then batch1 ----
        gather_lerp_store(tap, kh, kw, G, 0, grp, gl, sS, sPW);
        gather_issue(kh, kw, G, 4, grp, gl, nbase, in_cl, sPYp, sPXp);
        gather_lerp_store(tap, kh, kw, G, 4, grp, gl, sS, sPW);

        __syncthreads();                   // drains glds+gathers; sS+sW ready

        // ---- prefetch next tap's batch0 (flies during MFMA) ----
        if (tap < 8) {
            const int tap1 = tap + 1;
            const int kh1 = tap1 / 3;
            const int kw1 = tap1 - kh1 * 3;
            gather_issue(kh1, kw1, G, 0, grp, gl, nbase, in_cl, sPYp, sPXp);
        }

        // ---- phase B: 2x2 wave tile; A-frags LINEAR from sW (no conflict) ---
#pragma unroll
        for (int ks = 0; ks < 4; ++ks) {
            const int sw = ((ks << 2) | quad) ^ (l15 & 7);
            f16x8 bfr[4];
#pragma unroll
            for (int nt = 0; nt < 4; ++nt)
                bfr[nt] = *(const f16x8*)&sS[(wn * 64 + nt * 16 + l15) * 128 + sw * 8];
#pragma unroll
            for (int mt = 0; mt < 4; ++mt) {
                const int mtg = (wm << 2) | mt;            // global o-frag 0..7
                U4H AF;
                AF.u = sW[(((mtg << 2) | ks) << 6) + lane]; // base + lane*16B
#pragma unroll
                for (int nt = 0; nt < 4; ++nt)
                    acc[mt][nt] = __builtin_amdgcn_mfma_f32_16x16x32_f16(AF.f, bfr[nt], acc[mt][nt], 0, 0, 0);
            }
        }
        __syncthreads();                   // protect sS/sW overwrite next tap
    }

    // ---- epilogue: direct strided stores (2x2-tile mapping, v6-proven) ----
#pragma unroll
    for (int nt = 0; nt < 4; ++nt) {
        int p    = wn * 64 + nt * 16 + l15;
        int prel = pbase + p;
        int rem2 = min(prel, PIXPER - 1);
        float* obase = out + (size_t)n * (COUT * PIXPER) + rem2;
        if (prel < PIXPER) {
#pragma unroll
            for (int mt = 0; mt < 4; ++mt) {
                int o0 = wm * 64 + (mt << 4) + (quad << 2);
                float4 bs = *(const float4*)(bias + o0);
                f32x4 a0 = acc[mt][nt];
                obase[(size_t)(o0 + 0) * PIXPER] = a0[0] + bs.x;
                obase[(size_t)(o0 + 1) * PIXPER] = a0[1] + bs.y;
                obase[(size_t)(o0 + 2) * PIXPER] = a0[2] + bs.z;
                obase[(size_t)(o0 + 3) * PIXPER] = a0[3] + bs.w;
            }
        }
    }
}

// ---------------------------------------------------------------------------
extern "C" void kernel_launch(void* const* d_in, const int* in_sizes, int n_in,
                              void* d_out, int out_size, void* d_ws, size_t ws_size,
                              hipStream_t stream) {
    const float* inputs = (const float*)d_in[0];   // [8,128,128,128]
    const float* weight = (const float*)d_in[1];   // [128,128,3,3]
    const float* rates  = (const float*)d_in[2];   // [1,1,32,32]
    const float* bias   = (const float*)d_in[3];   // [128]
    float* out = (float*)d_out;                    // [8,128,126,126]

    char* ws = (char*)d_ws;
    _Float16* in_cl = (_Float16*)ws;                         // 33,554,432 B
    _Float16* wtp   = (_Float16*)(ws + 33554432);            //    294,912 B

    transpose_w_kernel<<<64, 256, 0, stream>>>(weight, wtp);
    transpose_in_kernel<<<4096, 256, 0, stream>>>(inputs, in_cl);
    adc_main<<<NBLK, 256, 0, stream>>>(in_cl, wtp, rates, bias, out);
}